// Round 2
// baseline (925.935 us; speedup 1.0000x reference)
//
#include <hip/hip_runtime.h>

// IBRNet aggregator, fully fused, fp32, register-resident (no LDS).
// Layout (all fp32):
//  features   (2,8,32,32^3)   idx ((b*8+n)*32+c)*32768+v
//  mask/depth (2,8,1,32^3)    idx (b*8+n)*32768+v
//  voxel_dir  (2,8,3,32^3)    idx ((b*8+n)*3+d)*32768+v
//  weights row-major [o][i];  out (2,32,32^3) idx (b*32+c)*32768+v
//
// One wave = 8 voxels x 8 views (n = lane>>3, vsub = lane&7).
// Cross-view reductions: shfl_xor butterfly over lanemask {8,16,32}.
// All MLP output loops are FULLY UNROLLED -> hidden vectors are static
// register arrays, weight rows are static-offset scalar loads (SGPR
// operands feed v_fmac directly). Stat layer: per-voxel, so each lane
// computes only its 4 output rows (vector loads of stat_w, L1-broadcast).

#define G3 32768

__device__ __forceinline__ float eluf(float x) {
    return x > 0.0f ? x : __expf(x) - 1.0f;
}
__device__ __forceinline__ float sigmoidf(float x) {
    return 1.0f / (1.0f + __expf(-x));
}
__device__ __forceinline__ float red8(float v) {
    v += __shfl_xor(v, 8, 64);
    v += __shfl_xor(v, 16, 64);
    v += __shfl_xor(v, 32, 64);
    return v;
}

// 4-chain dot of a uniform weight row with a register vector.
template <int K>
__device__ __forceinline__ float dotrow(const float* __restrict__ row,
                                        const float (&x)[K]) {
    float a0 = 0.f, a1 = 0.f, a2 = 0.f, a3 = 0.f;
#pragma unroll
    for (int c = 0; c < K; c += 4) {
        a0 += row[c + 0] * x[c + 0];
        a1 += row[c + 1] * x[c + 1];
        a2 += row[c + 2] * x[c + 2];
        a3 += row[c + 3] * x[c + 3];
    }
    return (a0 + a1) + (a2 + a3);
}

__global__ __launch_bounds__(128) void ibr_kernel(
    const float* __restrict__ features, const float* __restrict__ mask,
    const float* __restrict__ vdepth, const float* __restrict__ vdir,
    const float* __restrict__ rde_w1, const float* __restrict__ rde_b1,
    const float* __restrict__ rde_w2, const float* __restrict__ rde_b2,
    const float* __restrict__ base_w1, const float* __restrict__ base_b1,
    const float* __restrict__ base_w2, const float* __restrict__ base_b2,
    const float* __restrict__ vis_w1, const float* __restrict__ vis_b1,
    const float* __restrict__ vis_w2, const float* __restrict__ vis_b2,
    const float* __restrict__ vis2_w1, const float* __restrict__ vis2_b1,
    const float* __restrict__ vis2_w2, const float* __restrict__ vis2_b2,
    const float* __restrict__ stat_w, const float* __restrict__ stat_b,
    float* __restrict__ out) {
    const int lane = threadIdx.x & 63;
    const int w = blockIdx.x * 2 + (threadIdx.x >> 6);  // wave id 0..8191
    const int n = lane >> 3;                            // view 0..7
    const int vsub = lane & 7;
    const int b = w >> 12;  // 4096 waves per batch
    const int v = ((w & 4095) << 3) + vsub;
    const int bn = b * 8 + n;

    // ---------------- phase A: rde MLP, feats, mask-weighted mean/var ------
    const float m = mask[bn * G3 + v];
    const float r0 = vdir[(bn * 3 + 0) * G3 + v];
    const float r1 = vdir[(bn * 3 + 1) * G3 + v];
    const float r2 = vdir[(bn * 3 + 2) * G3 + v];
    const float r3 = vdepth[bn * G3 + v];

    float h16[16];
#pragma unroll
    for (int o = 0; o < 16; ++o) {
        float a = rde_b1[o] + rde_w1[o * 4 + 0] * r0 + rde_w1[o * 4 + 1] * r1 +
                  rde_w1[o * 4 + 2] * r2 + rde_w1[o * 4 + 3] * r3;
        h16[o] = eluf(a);
    }
    float f[32];
#pragma unroll
    for (int o = 0; o < 32; ++o) {
        float a = rde_b2[o];
#pragma unroll
        for (int c = 0; c < 16; ++c) a += rde_w2[o * 16 + c] * h16[c];
        f[o] = eluf(a) + features[(bn * 32 + o) * G3 + v];
    }

    const float msum = red8(m);
    const float wt = m / (msum + 1e-8f);

    float mean[32], var[32];
#pragma unroll
    for (int c = 0; c < 32; ++c) mean[c] = red8(wt * f[c]);
#pragma unroll
    for (int c = 0; c < 32; ++c) {
        float d = f[c] - mean[c];
        var[c] = red8(wt * d * d);
    }

    // ---------------- base MLP: 96 -> 64 -> 32 (all registers) -------------
    float h[64];
#pragma unroll
    for (int o = 0; o < 64; ++o) {
        const float* row = base_w1 + o * 96;
        float a = dotrow<32>(row, mean) + dotrow<32>(row + 32, var) +
                  dotrow<32>(row + 64, f) + base_b1[o];
        h[o] = eluf(a);
    }
    float x[32];
#pragma unroll
    for (int o = 0; o < 32; ++o) {
        x[o] = eluf(dotrow<64>(base_w2 + o * 64, h) + base_b2[o]);
    }

    // ---------------- vis MLP: (x*wt) 32 -> 32 -> 33 -----------------------
    float xin[32];
#pragma unroll
    for (int c = 0; c < 32; ++c) xin[c] = x[c] * wt;
    float hv[32];
#pragma unroll
    for (int o = 0; o < 32; ++o) {
        hv[o] = eluf(dotrow<32>(vis_w1 + o * 32, xin) + vis_b1[o]);
    }
    float xr[32];
#pragma unroll
    for (int o = 0; o < 32; ++o) {
        xr[o] = eluf(dotrow<32>(vis_w2 + o * 32, hv) + vis_b2[o]);
    }
    const float visn =
        sigmoidf(eluf(dotrow<32>(vis_w2 + 32 * 32, hv) + vis_b2[32])) * m;
#pragma unroll
    for (int c = 0; c < 32; ++c) x[c] += xr[c];

    // ---------------- vis2 MLP: (x*visn) 32 -> 32 -> 1 ---------------------
#pragma unroll
    for (int c = 0; c < 32; ++c) xin[c] = x[c] * visn;
#pragma unroll
    for (int o = 0; o < 32; ++o) {
        hv[o] = eluf(dotrow<32>(vis2_w1 + o * 32, xin) + vis2_b1[o]);
    }
    const float visv = sigmoidf(dotrow<32>(vis2_w2, hv) + vis2_b2[0]) * m;

    // ---------------- phase C: vis-weighted mean/var + stat conv -----------
    const float b0 = red8(visv);
    const float inv = 1.0f / (b0 + 1e-8f);
    const float wt2 = visv * inv;
    const float wm = b0 * inv * 0.125f;  // mean of weight over views

    float mean2[32], var2[32];
#pragma unroll
    for (int c = 0; c < 32; ++c) mean2[c] = red8(wt2 * x[c]);
#pragma unroll
    for (int c = 0; c < 32; ++c) {
        float d = x[c] - mean2[c];
        var2[c] = red8(wt2 * d * d);
    }

    // stat layer is per-voxel: each lane computes only its 4 output rows
    // (o = 4n..4n+3) with per-lane vector loads (8 lanes share a row -> L1
    // broadcast), then writes them directly.
    const int obase = n * 4;
#pragma unroll
    for (int j = 0; j < 4; ++j) {
        const float* row = stat_w + (obase + j) * 65;
        float a = dotrow<32>(row, mean2) + dotrow<32>(row + 32, var2) +
                  row[64] * wm + stat_b[obase + j];
        out[(b * 32 + obase + j) * G3 + v] = eluf(a);
    }
}

extern "C" void kernel_launch(void* const* d_in, const int* in_sizes, int n_in,
                              void* d_out, int out_size, void* d_ws,
                              size_t ws_size, hipStream_t stream) {
    const float* features = (const float*)d_in[0];
    const float* mask = (const float*)d_in[1];
    const float* vdepth = (const float*)d_in[2];
    const float* vdir = (const float*)d_in[3];
    const float* rde_w1 = (const float*)d_in[4];
    const float* rde_b1 = (const float*)d_in[5];
    const float* rde_w2 = (const float*)d_in[6];
    const float* rde_b2 = (const float*)d_in[7];
    const float* base_w1 = (const float*)d_in[8];
    const float* base_b1 = (const float*)d_in[9];
    const float* base_w2 = (const float*)d_in[10];
    const float* base_b2 = (const float*)d_in[11];
    const float* vis_w1 = (const float*)d_in[12];
    const float* vis_b1 = (const float*)d_in[13];
    const float* vis_w2 = (const float*)d_in[14];
    const float* vis_b2 = (const float*)d_in[15];
    const float* vis2_w1 = (const float*)d_in[16];
    const float* vis2_b1 = (const float*)d_in[17];
    const float* vis2_w2 = (const float*)d_in[18];
    const float* vis2_b2 = (const float*)d_in[19];
    const float* stat_w = (const float*)d_in[20];
    const float* stat_b = (const float*)d_in[21];

    // 8192 waves total; 128-thread blocks (2 waves) -> 4096 blocks
    ibr_kernel<<<4096, 128, 0, stream>>>(
        features, mask, vdepth, vdir, rde_w1, rde_b1, rde_w2, rde_b2, base_w1,
        base_b1, base_w2, base_b2, vis_w1, vis_b1, vis_w2, vis_b2, vis2_w1,
        vis2_b1, vis2_w2, vis2_b2, stat_w, stat_b, (float*)d_out);
}

// Round 3
// 471.855 us; speedup vs baseline: 1.9623x; 1.9623x over previous
//
#include <hip/hip_runtime.h>

// IBRNet aggregator, fused fp32. R3: rolled loops (I$-resident), view index
// in LOW lane bits (cheap xor-1/2/4 reductions), single-pass mean/var,
// 32-row LDS scratch (8KB/wave), 256-thread blocks (full-line fetches).
//
// Layout (all fp32):
//  features   (2,8,32,32^3)   idx ((b*8+n)*32+c)*32768+v
//  mask/depth (2,8,1,32^3)    idx (b*8+n)*32768+v
//  voxel_dir  (2,8,3,32^3)    idx ((b*8+n)*3+d)*32768+v
//  weights row-major [o][i];  out (2,32,32^3) idx (b*32+c)*32768+v
//
// Wave = 8 views x 8 voxels: n = lane&7, vsub = lane>>3.
// Cross-view sum = shfl_xor {1,2,4} (within 32-lane halves).
// MLP o-loops rolled (unroll 2): weight rows via wave-uniform scalar loads;
// dynamic-indexed layer outputs round-trip a 32-row per-tid LDS column
// (same-thread write/read: no barrier needed).
// Single-pass weighted var: var = E[x^2] - mu^2*(2 - s), s = sum(w)
// (exact algebra for the reference's  sum w (x - mu)^2  with mu = sum w x).

#define G3 32768

__device__ __forceinline__ float eluf(float x) {
    return x > 0.0f ? x : __expf(x) - 1.0f;
}
__device__ __forceinline__ float sigmoidf(float x) {
    return 1.0f / (1.0f + __expf(-x));
}
__device__ __forceinline__ float red8(float v) {
    v += __shfl_xor(v, 1, 64);
    v += __shfl_xor(v, 2, 64);
    v += __shfl_xor(v, 4, 64);
    return v;
}

template <int K>
__device__ __forceinline__ float dotrow(const float* __restrict__ row,
                                        const float (&x)[K]) {
    float a0 = 0.f, a1 = 0.f, a2 = 0.f, a3 = 0.f;
#pragma unroll
    for (int c = 0; c < K; c += 4) {
        a0 += row[c + 0] * x[c + 0];
        a1 += row[c + 1] * x[c + 1];
        a2 += row[c + 2] * x[c + 2];
        a3 += row[c + 3] * x[c + 3];
    }
    return (a0 + a1) + (a2 + a3);
}

__global__ __launch_bounds__(256, 4) void ibr_kernel(
    const float* __restrict__ features, const float* __restrict__ mask,
    const float* __restrict__ vdepth, const float* __restrict__ vdir,
    const float* __restrict__ rde_w1, const float* __restrict__ rde_b1,
    const float* __restrict__ rde_w2, const float* __restrict__ rde_b2,
    const float* __restrict__ base_w1, const float* __restrict__ base_b1,
    const float* __restrict__ base_w2, const float* __restrict__ base_b2,
    const float* __restrict__ vis_w1, const float* __restrict__ vis_b1,
    const float* __restrict__ vis_w2, const float* __restrict__ vis_b2,
    const float* __restrict__ vis2_w1, const float* __restrict__ vis2_b1,
    const float* __restrict__ vis2_w2, const float* __restrict__ vis2_b2,
    const float* __restrict__ stat_w, const float* __restrict__ stat_b,
    float* __restrict__ out) {
    __shared__ float scratch[32 * 256];  // [row][tid], 32 KB per 4-wave block

    const int tid = threadIdx.x;
    const int lane = tid & 63;
    const int n = lane & 7;      // view (low bits -> cheap shuffles)
    const int vsub = lane >> 3;  // voxel-within-wave
    const int w = blockIdx.x * 4 + (tid >> 6);  // wave id 0..8191
    const int b = w >> 12;
    const int v = ((w & 4095) << 3) + vsub;  // block covers 32 consec voxels
    const int bn = b * 8 + n;

    // ---- input loads issued early (overlap with rde compute) --------------
    const float m = mask[bn * G3 + v];
    const float r0 = vdir[(bn * 3 + 0) * G3 + v];
    const float r1 = vdir[(bn * 3 + 1) * G3 + v];
    const float r2 = vdir[(bn * 3 + 2) * G3 + v];
    const float r3 = vdepth[bn * G3 + v];
    float fin[32];
#pragma unroll
    for (int c = 0; c < 32; ++c) fin[c] = features[(bn * 32 + c) * G3 + v];

    // ---- rde MLP: 4 -> 16 -> 32, feats = features + rde -------------------
    float h16[16];
#pragma unroll
    for (int o = 0; o < 16; ++o) {
        float a = rde_b1[o] + rde_w1[o * 4 + 0] * r0 + rde_w1[o * 4 + 1] * r1 +
                  rde_w1[o * 4 + 2] * r2 + rde_w1[o * 4 + 3] * r3;
        h16[o] = eluf(a);
    }
    float f[32];
#pragma unroll
    for (int o = 0; o < 32; ++o) {
        float a = rde_b2[o];
#pragma unroll
        for (int c = 0; c < 16; ++c) a += rde_w2[o * 16 + c] * h16[c];
        f[o] = eluf(a) + fin[o];
    }

    // ---- mask-weighted mean/var (single pass) -----------------------------
    const float msum = red8(m);
    const float invA = 1.0f / (msum + 1e-8f);
    const float wt = m * invA;
    const float sA = msum * invA;  // sum of weights (~1)

    float mean[32], var[32];
#pragma unroll
    for (int c = 0; c < 32; ++c) {
        const float p = wt * f[c];
        mean[c] = red8(p);
        var[c] = red8(p * f[c]);  // E[x^2] for now
    }
#pragma unroll
    for (int c = 0; c < 32; ++c)
        var[c] = var[c] - mean[c] * mean[c] * (2.0f - sA);

    // ---- base MLP: 96 -> 64 -> 32 -----------------------------------------
    float h0[32], h1[32];
#pragma unroll 2
    for (int o = 0; o < 32; ++o) {
        const float* row = base_w1 + o * 96;
        float a = dotrow<32>(row, mean) + dotrow<32>(row + 32, var) +
                  dotrow<32>(row + 64, f) + base_b1[o];
        scratch[o * 256 + tid] = eluf(a);
    }
#pragma unroll
    for (int c = 0; c < 32; ++c) h0[c] = scratch[c * 256 + tid];
#pragma unroll 2
    for (int o = 0; o < 32; ++o) {
        const float* row = base_w1 + (o + 32) * 96;
        float a = dotrow<32>(row, mean) + dotrow<32>(row + 32, var) +
                  dotrow<32>(row + 64, f) + base_b1[o + 32];
        scratch[o * 256 + tid] = eluf(a);
    }
#pragma unroll
    for (int c = 0; c < 32; ++c) h1[c] = scratch[c * 256 + tid];

    float x[32];
#pragma unroll 2
    for (int o = 0; o < 32; ++o) {
        const float* row = base_w2 + o * 64;
        scratch[o * 256 + tid] =
            eluf(dotrow<32>(row, h0) + dotrow<32>(row + 32, h1) + base_b2[o]);
    }
#pragma unroll
    for (int c = 0; c < 32; ++c) x[c] = scratch[c * 256 + tid];

    // ---- vis MLP: (x*wt) 32 -> 32 -> 33 -----------------------------------
    float xin[32];
#pragma unroll
    for (int c = 0; c < 32; ++c) xin[c] = x[c] * wt;
    float hv[32];
#pragma unroll 2
    for (int o = 0; o < 32; ++o) {
        scratch[o * 256 + tid] =
            eluf(dotrow<32>(vis_w1 + o * 32, xin) + vis_b1[o]);
    }
#pragma unroll
    for (int c = 0; c < 32; ++c) hv[c] = scratch[c * 256 + tid];
#pragma unroll 2
    for (int o = 0; o < 32; ++o) {
        scratch[o * 256 + tid] =
            eluf(dotrow<32>(vis_w2 + o * 32, hv) + vis_b2[o]);
    }
    const float visn =
        sigmoidf(eluf(dotrow<32>(vis_w2 + 32 * 32, hv) + vis_b2[32])) * m;
#pragma unroll
    for (int c = 0; c < 32; ++c) x[c] += scratch[c * 256 + tid];

    // ---- vis2 MLP: (x*visn) 32 -> 32 -> 1 ---------------------------------
#pragma unroll
    for (int c = 0; c < 32; ++c) xin[c] = x[c] * visn;
#pragma unroll 2
    for (int o = 0; o < 32; ++o) {
        scratch[o * 256 + tid] =
            eluf(dotrow<32>(vis2_w1 + o * 32, xin) + vis2_b1[o]);
    }
#pragma unroll
    for (int c = 0; c < 32; ++c) hv[c] = scratch[c * 256 + tid];
    const float visv = sigmoidf(dotrow<32>(vis2_w2, hv) + vis2_b2[0]) * m;

    // ---- vis-weighted mean/var (single pass) + stat layer -----------------
    const float b0 = red8(visv);
    const float invC = 1.0f / (b0 + 1e-8f);
    const float wt2 = visv * invC;
    const float sC = b0 * invC;
    const float wm = sC * 0.125f;  // mean over views of weight

    float mean2[32], var2[32];
#pragma unroll
    for (int c = 0; c < 32; ++c) {
        const float p = wt2 * x[c];
        mean2[c] = red8(p);
        var2[c] = red8(p * x[c]);
    }
#pragma unroll
    for (int c = 0; c < 32; ++c)
        var2[c] = var2[c] - mean2[c] * mean2[c] * (2.0f - sC);

    // stat layer is per-voxel: each lane computes its 4 rows (o = 4n..4n+3)
    const int obase = n * 4;
#pragma unroll
    for (int j = 0; j < 4; ++j) {
        const float* row = stat_w + (obase + j) * 65;
        float a = dotrow<32>(row, mean2) + dotrow<32>(row + 32, var2) +
                  row[64] * wm + stat_b[obase + j];
        out[(b * 32 + obase + j) * G3 + v] = eluf(a);
    }
}

extern "C" void kernel_launch(void* const* d_in, const int* in_sizes, int n_in,
                              void* d_out, int out_size, void* d_ws,
                              size_t ws_size, hipStream_t stream) {
    const float* features = (const float*)d_in[0];
    const float* mask = (const float*)d_in[1];
    const float* vdepth = (const float*)d_in[2];
    const float* vdir = (const float*)d_in[3];
    const float* rde_w1 = (const float*)d_in[4];
    const float* rde_b1 = (const float*)d_in[5];
    const float* rde_w2 = (const float*)d_in[6];
    const float* rde_b2 = (const float*)d_in[7];
    const float* base_w1 = (const float*)d_in[8];
    const float* base_b1 = (const float*)d_in[9];
    const float* base_w2 = (const float*)d_in[10];
    const float* base_b2 = (const float*)d_in[11];
    const float* vis_w1 = (const float*)d_in[12];
    const float* vis_b1 = (const float*)d_in[13];
    const float* vis_w2 = (const float*)d_in[14];
    const float* vis_b2 = (const float*)d_in[15];
    const float* vis2_w1 = (const float*)d_in[16];
    const float* vis2_b1 = (const float*)d_in[17];
    const float* vis2_w2 = (const float*)d_in[18];
    const float* vis2_b2 = (const float*)d_in[19];
    const float* stat_w = (const float*)d_in[20];
    const float* stat_b = (const float*)d_in[21];

    // 8192 waves total; 256-thread blocks (4 waves) -> 2048 blocks
    ibr_kernel<<<2048, 256, 0, stream>>>(
        features, mask, vdepth, vdir, rde_w1, rde_b1, rde_w2, rde_b2, base_w1,
        base_b1, base_w2, base_b2, vis_w1, vis_b1, vis_w2, vis_b2, vis2_w1,
        vis2_b1, vis2_w2, vis2_b2, stat_w, stat_b, (float*)d_out);
}